// Round 9
// baseline (2336.897 us; speedup 1.0000x reference)
//
#include <hip/hip_runtime.h>

// AdEx Euler integration, fp32 port of the jax/numpy reference.
// Sequential scan over T=40000 steps; N=1024 neurons -> 16 waves on 16 CUs.
// Measured: wall tracks the per-step DEPENDENT CHAIN ~1:1 (R2,R5,R6,R7),
// plus a ~75 cyc/step constant. VALU issue is ~20 cyc of it; the rest is
// global-store WAR stalls: VGPR=32 proves the compiler sinks the 2 stores
// into every step (burst reg-arrays can't exist), so store-data regs rotate
// in a tiny window and each step waits vmcnt on ~200-400 cyc completions.
// Measured: trajectory is bit-stable under increment-level rounding
// perturbations (R5-R8 all left absmax EXACTLY 4.882812e-04).
//
// R1: batched uniform I_ext scalar loads                     8217 -> 7055 us
// R2: IEEE divs -> fp64 reciprocal-mul (bit-exact)           7055 -> 4193 us
// R3: burst-store buffering                                  4193 -> 4007 us
// R4: 2 neurons/lane -> REGRESSED (serialized chains)        reverted
// R5: raw v_exp_f32, folded log2e/delta_T                    4007 -> 2878 us
// R6: fold dt/tau, dt/tau_w; all-f32 body                    2878 -> 2255 us
// R8: 6-dep V chain (pre-scaled exp, fma reassoc)            2255 -> 1885 us
// R9 (this): kill the store-WAR stall structurally: steps write (V,w) to
//     LDS (ds_write_b32, hidden); every 16 steps a flush ds_read_b128s and
//     issues 8 global_store_dwordx4 (vs 32 scalar stores), data regs only
//     reused next flush ~1500 cyc later. Chain -1 dep: V_T folded into exp
//     constant (c2 = c_off - V_T*c_exp), V_rest folded into I batch.

__device__ __forceinline__ float exp2_raw(float u) {
    float r;
    asm("v_exp_f32 %0, %1" : "=v"(r) : "v"(u));   // r = 2^u, ~1 ulp
    return r;
}

__global__ void __launch_bounds__(64, 1) adex_kernel(
    const float* __restrict__ I_ext,
    const float* __restrict__ V0,
    const float* __restrict__ w0,
    const float* __restrict__ p_V_rest,
    const float* __restrict__ p_V_reset,
    const float* __restrict__ p_V_T,
    const float* __restrict__ p_V_thres,
    const float* __restrict__ p_delta_T,
    const float* __restrict__ p_R,
    const float* __restrict__ p_tau,
    const float* __restrict__ p_tau_w,
    const float* __restrict__ p_a,
    const float* __restrict__ p_b,
    float* __restrict__ out,
    int T, int N)
{
#pragma clang fp contract(off)
    // Per-batch LDS staging: 16 steps x 64 lanes, V and w in separate areas
    // so the flush can b128-read 4 consecutive neurons of one step.
    __shared__ float ldsV[16 * 64];
    __shared__ float ldsW[16 * 64];

    const int l     = threadIdx.x;            // 0..63
    const int nbase = blockIdx.x * 64;
    int n = nbase + l;
    if (n >= N) n = N - 1;   // uniform control flow (scalar I loads)

    const float V_rest  = *p_V_rest;
    const float V_reset = *p_V_reset;
    const float V_T     = *p_V_T;
    const float V_thres = *p_V_thres;
    const float delta_T = *p_delta_T;
    const float R       = *p_R;
    const float tau     = *p_tau;
    const float tau_w   = *p_tau_w;
    const float a       = *p_a;
    const float b       = *p_b;
    const float dt      = 5e-5f;

    // Folded constants, computed in f64, rounded once to f32.
    const double dT  = (double)delta_T;
    const float c_exp = (float)(1.4426950408889634 / dT);            // log2e/dT
    const float c_v   = (float)((double)dt / (double)tau);           // dt/tau
    const float c_w   = (float)((double)dt / (double)tau_w);         // dt/tau_w
    // exp term pre-scaled for integration AND V_T pre-folded:
    // dT*exp((V-V_T)/dT)*dt/tau = 2^(V*c_exp + c2)
    const double c_off = log2(dT * (double)dt / (double)tau);
    const float c2    = (float)(c_off - (double)V_T * (1.4426950408889634 / dT));
    const float nR    = -R;

    float V = V0[n];
    float w = w0[n];

    // Flush geometry: lane l covers step (g*4 + l/16), neurons 4*(l&15)..+3.
    const int srow = l >> 4;          // 0..3
    const int scol = (l & 15) << 2;   // 0,4,..,60

    float* outVb = out + nbase;                     // block-base V rows
    float* outWb = out + (size_t)T * N + nbase;     // block-base w rows

    // One Euler step: state to LDS (cheap, hidden), pure-f32 4-dep V chain.
#define ADEX_STEP(j, RIr_k)                                         \
    {                                                               \
        ldsV[(j) * 64 + l] = V;                                     \
        ldsW[(j) * 64 + l] = w;                                     \
        float ex3 = exp2_raw(fmaf(V, c_exp, c2));                   \
        float t1  = V - V_rest;                                     \
        float u   = fmaf(nR, w, (RIr_k) - V);                       \
        float Vp  = fmaf(u, c_v, V);                                \
        float Vn  = Vp + ex3;                                       \
        float tw  = fmaf(a, t1, -w);                                \
        float wn  = fmaf(tw, c_w, w);                               \
        bool  spike = V > V_thres;                                  \
        Vn = spike ? V_reset : Vn;                                  \
        wn = spike ? (wn + b) : wn;                                 \
        V = Vn;                                                     \
        w = wn;                                                     \
    }

    // Flush 16 steps: 4 b128 LDS reads + 4 dwordx4 global stores per array.
    // Store-data regs are reused only next flush (~1500 cyc) -> no WAR bind.
#define ADEX_FLUSH()                                                \
    {                                                               \
        __syncthreads();                                            \
        _Pragma("unroll")                                           \
        for (int g = 0; g < 4; ++g) {                               \
            int st = g * 4 + srow;                                  \
            float4 v = *reinterpret_cast<const float4*>(            \
                &ldsV[st * 64 + scol]);                             \
            *reinterpret_cast<float4*>(                             \
                &outVb[(size_t)st * N + scol]) = v;                 \
            float4 wv = *reinterpret_cast<const float4*>(           \
                &ldsW[st * 64 + scol]);                             \
            *reinterpret_cast<float4*>(                             \
                &outWb[(size_t)st * N + scol]) = wv;                \
        }                                                           \
        __syncthreads();                                            \
        outVb += (size_t)16 * N;                                    \
        outWb += (size_t)16 * N;                                    \
    }

    // Double-buffered uniform I batches; Ar = R*I + V_rest precomputed so
    // the step uses (Ar - V) directly (one rounding fold, increment-level).
    // I_ext has T+5 elements; prefetch base clamped so max index <= T+4.
    float A[16], B[16];
#pragma unroll
    for (int j = 0; j < 16; ++j) A[j] = R * I_ext[j] + V_rest;

    for (int kb = 0; kb < T; kb += 32) {
        // prefetch B = I[kb+16 .. kb+31]  (kb <= T-32 -> max idx T-1, ok)
#pragma unroll
        for (int j = 0; j < 16; ++j) B[j] = R * I_ext[kb + 16 + j] + V_rest;

#pragma unroll
        for (int j = 0; j < 16; ++j) ADEX_STEP(j, A[j]);
        ADEX_FLUSH();

        // prefetch A = I[kb+32 .. kb+47], clamped (pb+15 <= T+4); clamped
        // batch is only reached when the loop exits, never consumed stale.
        {
            int pb = kb + 32;
            if (pb > T - 11) pb = T - 11;
#pragma unroll
            for (int j = 0; j < 16; ++j) A[j] = R * I_ext[pb + j] + V_rest;
        }

#pragma unroll
        for (int j = 0; j < 16; ++j) ADEX_STEP(j, B[j]);
        ADEX_FLUSH();
    }
#undef ADEX_STEP
#undef ADEX_FLUSH
}

extern "C" void kernel_launch(void* const* d_in, const int* in_sizes, int n_in,
                              void* d_out, int out_size, void* d_ws, size_t ws_size,
                              hipStream_t stream) {
    const float* I_ext = (const float*)d_in[0];
    const float* V0    = (const float*)d_in[1];
    const float* w0    = (const float*)d_in[2];

    const int N = in_sizes[1];          // 1024
    const int T = out_size / (2 * N);   // 40000

    const int block = 64;
    const int grid  = (N + block - 1) / block;   // 16 blocks

    adex_kernel<<<grid, block, 0, stream>>>(
        I_ext, V0, w0,
        (const float*)d_in[3],  // V_rest
        (const float*)d_in[4],  // V_reset
        (const float*)d_in[5],  // V_T
        (const float*)d_in[6],  // V_thres
        (const float*)d_in[7],  // delta_T
        (const float*)d_in[8],  // R
        (const float*)d_in[9],  // tau
        (const float*)d_in[10], // tau_w
        (const float*)d_in[11], // a
        (const float*)d_in[12], // b
        (float*)d_out, T, N);
}